// Round 2
// baseline (1206.258 us; speedup 1.0000x reference)
//
#include <hip/hip_runtime.h>
#include <math.h>

namespace {

constexpr int B_ = 8, C_ = 256, H_ = 128, W_ = 192;
constexpr int R_ = 4, ND = 9;              // 2R+1 displacements per axis
constexpr int TH = 8;                       // h rows per block
constexpr int TW = 32;                      // w cols per block
constexpr int WPT = 8;                      // w positions per thread
constexpr int NTHREADS = 320;               // 5 waves: dyi = tid>>5 (wave4 upper half idle)
constexpr int KC = 4;                       // channels per LDS chunk
constexpr int NCHUNK = C_ / KC;             // 64
constexpr int F1S = 36;                     // f1 row stride (36 mod 32 = 4 -> bank spread)
constexpr int F2R = TH + 2 * R_;            // 16 rows
constexpr int F2W = TW + 16;                // 48 staged cols (w0-8 .. w0+39)
constexpr int F2S = 68;                     // f2 row stride (68 mod 32 = 4)
constexpr int F1SLOTS = TH * TW / 4;        // 64 float4 slots per channel
constexpr int F2SLOTS = F2R * (F2W / 4);    // 192
constexpr int NSLOTS = F1SLOTS + F2SLOTS;   // 256 staging threads

__global__ __launch_bounds__(NTHREADS, 4)
void local_corr_kernel(const float* __restrict__ f1g,
                       const float* __restrict__ f2g,
                       float* __restrict__ outg)
{
    __shared__ float sA[2][KC][TH][F1S];    //  9.2 KB
    __shared__ float sB[2][KC][F2R][F2S];   // 34.8 KB  (total 44 KB -> 3 blocks/CU)

    const int tid = threadIdx.x;
    const int w0  = blockIdx.x * TW;
    const int h0  = blockIdx.y * TH;
    const int b   = blockIdx.z;

    // compute role: wave owns one dy (wave4 lanes 32-63 idle in compute)
    const int  dyi    = tid >> 5;           // 0..9
    const bool active = dyi < ND;
    const int  l31    = tid & 31;
    const int  hloc   = l31 >> 2;           // 0..7
    const int  wl     = (l31 & 3) * WPT;    // 0,8,16,24

    // staging role: fixed spatial slot per thread across all channels
    const bool isStage = tid < NSLOTS;
    const bool isF1    = tid < F1SLOTS;
    int st_row = 0, st_col = 0, gh = 0, gx0 = 0;
    bool fast = false;
    const float* gsrc = nullptr;
    if (isStage) {
        if (isF1) {
            st_row = tid >> 3;              // 0..7
            st_col = (tid & 7) * 4;         // 0..28
            gh = h0 + st_row; gx0 = w0 + st_col;
            gsrc = f1g; fast = true;        // f1 tile always in-bounds
        } else {
            const int s2 = tid - F1SLOTS;   // 0..191
            st_row = s2 / 12;               // 0..15
            st_col = (s2 % 12) * 4;         // 0..44
            gh = h0 - R_ + st_row; gx0 = w0 - 8 + st_col;
            gsrc = f2g;
            fast = (gh >= 0) && (gh < H_) && (gx0 >= 0) && (gx0 + 3 < W_);
        }
    }

    float acc[WPT][ND];
#pragma unroll
    for (int i = 0; i < WPT; ++i)
#pragma unroll
        for (int j = 0; j < ND; ++j) acc[i][j] = 0.0f;

    float n0 = 0.f, n1 = 0.f, n2 = 0.f, n3 = 0.f;  // per-slot squared norms

    float4 vr[KC];

    auto loadChunk = [&](int c0) {
#pragma unroll
        for (int cc = 0; cc < KC; ++cc) {
            const size_t plane = ((size_t)b * C_ + (c0 + cc)) * H_;
            if (fast) {
                vr[cc] = *reinterpret_cast<const float4*>(gsrc + (plane + gh) * W_ + gx0);
            } else {
                const bool rok = (gh >= 0) && (gh < H_);
                const float* rp = gsrc + (plane + (rok ? gh : 0)) * W_;
                vr[cc].x = (rok && gx0 + 0 >= 0 && gx0 + 0 < W_) ? rp[gx0 + 0] : 0.f;
                vr[cc].y = (rok && gx0 + 1 >= 0 && gx0 + 1 < W_) ? rp[gx0 + 1] : 0.f;
                vr[cc].z = (rok && gx0 + 2 >= 0 && gx0 + 2 < W_) ? rp[gx0 + 2] : 0.f;
                vr[cc].w = (rok && gx0 + 3 >= 0 && gx0 + 3 < W_) ? rp[gx0 + 3] : 0.f;
            }
        }
    };

    auto writeChunk = [&](int buf) {
#pragma unroll
        for (int cc = 0; cc < KC; ++cc) {
            const float4 v = vr[cc];                 // vmcnt wait lands here
            n0 += v.x * v.x; n1 += v.y * v.y;
            n2 += v.z * v.z; n3 += v.w * v.w;
            if (isF1) *reinterpret_cast<float4*>(&sA[buf][cc][st_row][st_col]) = v;
            else      *reinterpret_cast<float4*>(&sB[buf][cc][st_row][st_col]) = v;
        }
    };

    auto computeChunk = [&](int buf) {
        if (!active) return;
#pragma unroll
        for (int cc = 0; cc < KC; ++cc) {
            float a[WPT];
            *reinterpret_cast<float4*>(&a[0]) =
                *reinterpret_cast<const float4*>(&sA[buf][cc][hloc][wl]);
            *reinterpret_cast<float4*>(&a[4]) =
                *reinterpret_cast<const float4*>(&sA[buf][cc][hloc][wl + 4]);
            float v[16];
            const float* fr = &sB[buf][cc][hloc + dyi][wl + 4];
#pragma unroll
            for (int k = 0; k < 4; ++k)
                *reinterpret_cast<float4*>(&v[4 * k]) =
                    *reinterpret_cast<const float4*>(&fr[4 * k]);
#pragma unroll
            for (int wi = 0; wi < WPT; ++wi)
#pragma unroll
                for (int dxi = 0; dxi < ND; ++dxi)
                    acc[wi][dxi] = fmaf(a[wi], v[wi + dxi], acc[wi][dxi]);
        }
    };

    // prologue: stage chunk 0
    if (isStage) { loadChunk(0); writeChunk(0); }
    __syncthreads();

    for (int t = 0; t < NCHUNK; ++t) {
        const bool more = (t + 1) < NCHUNK;
        if (isStage && more) loadChunk((t + 1) * KC);   // issue early (async)
        computeChunk(t & 1);
        if (isStage && more) writeChunk((t + 1) & 1);   // waits vmcnt here
        __syncthreads();
    }

    // norms into buffer 0 (done with data)
    if (isStage) {
        const float4 s = make_float4(n0, n1, n2, n3);
        if (isF1) *reinterpret_cast<float4*>(&sA[0][0][st_row][st_col]) = s;
        else      *reinterpret_cast<float4*>(&sB[0][0][st_row][st_col]) = s;
    }
    __syncthreads();

    if (active) {
        float inv1[WPT];
#pragma unroll
        for (int wi = 0; wi < WPT; ++wi) {
            const float n = sqrtf(sA[0][0][hloc][wl + wi]);
            inv1[wi] = 1.0f / fmaxf(n, 1e-12f);
        }
        float inv2[16];
        const float* nrow = &sB[0][0][hloc + dyi][wl + 4];
#pragma unroll
        for (int k = 0; k < 16; ++k) {
            const float n = sqrtf(nrow[k]);
            inv2[k] = 1.0f / fmaxf(n, 1e-12f);
        }

        const int h = h0 + hloc;
#pragma unroll
        for (int dxi = 0; dxi < ND; ++dxi) {
            const int d = dyi * ND + dxi;
            float o[WPT];
#pragma unroll
            for (int wi = 0; wi < WPT; ++wi)
                o[wi] = acc[wi][dxi] * inv1[wi] * inv2[wi + dxi];
            float* op = outg + (((size_t)b * (ND * ND) + d) * H_ + h) * W_ + w0 + wl;
            *reinterpret_cast<float4*>(&op[0]) = make_float4(o[0], o[1], o[2], o[3]);
            *reinterpret_cast<float4*>(&op[4]) = make_float4(o[4], o[5], o[6], o[7]);
        }
    }
}

} // namespace

extern "C" void kernel_launch(void* const* d_in, const int* in_sizes, int n_in,
                              void* d_out, int out_size, void* d_ws, size_t ws_size,
                              hipStream_t stream)
{
    (void)in_sizes; (void)n_in; (void)d_ws; (void)ws_size; (void)out_size;
    const float* f1 = (const float*)d_in[0];
    const float* f2 = (const float*)d_in[1];
    float* out = (float*)d_out;

    dim3 grid(W_ / TW, H_ / TH, B_);   // (6, 16, 8) = 768 blocks -> 3/CU uniform
    dim3 block(NTHREADS);              // 320 threads = 5 waves
    local_corr_kernel<<<grid, block, 0, stream>>>(f1, f2, out);
}

// Round 3
// 543.672 us; speedup vs baseline: 2.2187x; 2.2187x over previous
//
#include <hip/hip_runtime.h>
#include <math.h>

namespace {

constexpr int B_ = 8, C_ = 256, H_ = 128, W_ = 192;
constexpr int ND = 9;                  // 2R+1
constexpr int TH = 8;                  // h rows per block
constexpr int TWT = 64;                // w cols per block
constexpr int WPT = 8;                 // w per lane
constexpr int NTHREADS = 576;          // 9 waves, wave = dy
constexpr int KC = 4;                  // channels per chunk
constexpr int NCHUNK = C_ / KC;        // 64
// f1 staged [KC][TH][F1P] bf16, staged idx = w - w0, valid [0,64)
constexpr int F1P = 72;                // 144 B = 9 slots (odd) -> uniform banks
// f2 staged [KC][F2R][F2P] bf16, staged idx = w - (w0-4), valid [0,80)
constexpr int F2R = 16;
constexpr int F2P = 88;                // 176 B = 11 slots (odd)
constexpr int F1Q = TWT / 4;           // 16 quads per f1 row
constexpr int F1SLOTS = TH * F1Q;      // 128
constexpr int F2Q = 80 / 4;            // 20 quads per f2 row
constexpr int F2SLOTS = F2R * F2Q;     // 320
constexpr int NSLOTS = F1SLOTS + F2SLOTS; // 448 staging threads

__device__ __forceinline__ float bflo(unsigned u) { return __uint_as_float(u << 16); }
__device__ __forceinline__ float bfhi(unsigned u) { return __uint_as_float(u & 0xffff0000u); }

__global__ __launch_bounds__(NTHREADS)
void local_corr_kernel(const float* __restrict__ f1g,
                       const float* __restrict__ f2g,
                       float* __restrict__ outg)
{
    __shared__ unsigned short sf1[2][KC][TH][F1P];   //  9.2 KB
    __shared__ unsigned short sf2[2][KC][F2R][F2P];  // 22.5 KB

    // ---- XCD-chunked swizzle: each XCD owns one batch image (48 blocks) ----
    const int m   = blockIdx.x;            // 0..383
    const int n   = (m & 7) * 48 + (m >> 3);
    const int bx  = n % 3;
    const int by  = (n / 3) % 16;
    const int b   = n / 48;
    const int w0  = bx * TWT;
    const int h0  = by * TH;

    const int tid  = threadIdx.x;
    const int dyi  = tid >> 6;             // wave id = dy index 0..8
    const int lane = tid & 63;
    const int hs   = lane >> 3;            // 0..7
    const int wg   = lane & 7;             // 0..7; w = w0 + wg*8

    // ---- staging role: fixed spatial slot across all channels ----
    const bool isStage = tid < NSLOTS;
    const bool isF1    = tid < F1SLOTS;
    int srow = 0, squad = 0, gh = 0, gw = 0;
    const float* gsrc = f1g;
    if (isStage) {
        if (isF1) {
            srow = tid >> 4; squad = tid & 15;
            gh = h0 + srow; gw = w0 + squad * 4;
            gsrc = f1g;
        } else {
            const int s = tid - F1SLOTS;
            srow = s / F2Q; squad = s % F2Q;
            gh = h0 - 4 + srow; gw = w0 - 4 + squad * 4;
            gsrc = f2g;
        }
    }
    const bool rowOK = (gh >= 0) && (gh < H_);
    const bool m0 = rowOK && (gw + 0 >= 0) && (gw + 0 < W_);
    const bool m1 = rowOK && (gw + 1 >= 0) && (gw + 1 < W_);
    const bool m2 = rowOK && (gw + 2 >= 0) && (gw + 2 < W_);
    const bool m3 = rowOK && (gw + 3 >= 0) && (gw + 3 < W_);
    const int ghc = gh < 0 ? 0 : (gh >= H_ ? H_ - 1 : gh);
    const int gwc = gw < 0 ? 0 : (gw > W_ - 4 ? W_ - 4 : gw);
    const float* gptr = gsrc + ((size_t)b * C_ * H_ + (size_t)ghc * W_) * 1 + gwc
                        + (size_t)0; // plane added per-channel below
    // base without channel: gsrc + ((b*C + c)*H + ghc)*W + gwc
    const size_t gRowOff = (size_t)ghc * W_ + gwc;
    const size_t gImgOff = (size_t)b * C_ * (size_t)(H_ * W_);
    (void)gptr;

    float4 ld[KC];
    float4 nsq = make_float4(0.f, 0.f, 0.f, 0.f);

    auto issueLoads = [&](int c0) {
#pragma unroll
        for (int cc = 0; cc < KC; ++cc) {
            const float* p = gsrc + gImgOff + (size_t)(c0 + cc) * (H_ * W_) + gRowOff;
            ld[cc] = *reinterpret_cast<const float4*>(p);
        }
    };

    auto writeStage = [&](int buf) {
#pragma unroll
        for (int cc = 0; cc < KC; ++cc) {
            float x = m0 ? ld[cc].x : 0.f;
            float y = m1 ? ld[cc].y : 0.f;
            float z = m2 ? ld[cc].z : 0.f;
            float w = m3 ? ld[cc].w : 0.f;
            // truncating pack to bf16 (bias cancels: norms use reconstructed values)
            const unsigned u0 = (__float_as_uint(x) >> 16) | (__float_as_uint(y) & 0xffff0000u);
            const unsigned u1 = (__float_as_uint(z) >> 16) | (__float_as_uint(w) & 0xffff0000u);
            const float xr = bflo(u0), yr = bfhi(u0), zr = bflo(u1), wr = bfhi(u1);
            nsq.x = fmaf(xr, xr, nsq.x); nsq.y = fmaf(yr, yr, nsq.y);
            nsq.z = fmaf(zr, zr, nsq.z); nsq.w = fmaf(wr, wr, nsq.w);
            unsigned short* dst = isF1 ? &sf1[buf][cc][srow][squad * 4]
                                       : &sf2[buf][cc][srow][squad * 4];
            *reinterpret_cast<uint2*>(dst) = make_uint2(u0, u1);
        }
    };

    float acc[WPT][ND];
#pragma unroll
    for (int i = 0; i < WPT; ++i)
#pragma unroll
        for (int j = 0; j < ND; ++j) acc[i][j] = 0.f;

    const int f1rd = hs * (F1P * 2) + wg * 16;            // byte offset in [buf][cc]
    const int f2rd = (hs + dyi) * (F2P * 2) + wg * 16;    // window blocks wg..wg+2

    auto computeChunk = [&](int buf) {
        const char* b1 = reinterpret_cast<const char*>(&sf1[buf][0][0][0]);
        const char* b2 = reinterpret_cast<const char*>(&sf2[buf][0][0][0]);
#pragma unroll
        for (int cc = 0; cc < KC; ++cc) {
            const uint4 ua = *reinterpret_cast<const uint4*>(b1 + cc * (TH * F1P * 2) + f1rd);
            const uint4 u0 = *reinterpret_cast<const uint4*>(b2 + cc * (F2R * F2P * 2) + f2rd);
            const uint4 u1 = *reinterpret_cast<const uint4*>(b2 + cc * (F2R * F2P * 2) + f2rd + 16);
            const uint4 u2 = *reinterpret_cast<const uint4*>(b2 + cc * (F2R * F2P * 2) + f2rd + 32);
            float a[8];
            a[0] = bflo(ua.x); a[1] = bfhi(ua.x); a[2] = bflo(ua.y); a[3] = bfhi(ua.y);
            a[4] = bflo(ua.z); a[5] = bfhi(ua.z); a[6] = bflo(ua.w); a[7] = bfhi(ua.w);
            float v[24];
            v[0]  = bflo(u0.x); v[1]  = bfhi(u0.x); v[2]  = bflo(u0.y); v[3]  = bfhi(u0.y);
            v[4]  = bflo(u0.z); v[5]  = bfhi(u0.z); v[6]  = bflo(u0.w); v[7]  = bfhi(u0.w);
            v[8]  = bflo(u1.x); v[9]  = bfhi(u1.x); v[10] = bflo(u1.y); v[11] = bfhi(u1.y);
            v[12] = bflo(u1.z); v[13] = bfhi(u1.z); v[14] = bflo(u1.w); v[15] = bfhi(u1.w);
            v[16] = bflo(u2.x); v[17] = bfhi(u2.x); v[18] = bflo(u2.y); v[19] = bfhi(u2.y);
            v[20] = bflo(u2.z); v[21] = bfhi(u2.z); v[22] = bflo(u2.w); v[23] = bfhi(u2.w);
#pragma unroll
            for (int wi = 0; wi < WPT; ++wi)
#pragma unroll
                for (int d = 0; d < ND; ++d)
                    acc[wi][d] = fmaf(a[wi], v[wi + d], acc[wi][d]);
        }
    };

    // ---- main loop: issue loads(t+1) -> compute(t) -> cvt+write(t+1) -> barrier ----
    if (isStage) { issueLoads(0); writeStage(0); }
    __syncthreads();
    for (int t = 0; t < NCHUNK; ++t) {
        const int cur = t & 1;
        const bool more = (t + 1) < NCHUNK;
        if (isStage && more) issueLoads((t + 1) * KC);
        computeChunk(cur);
        if (isStage && more) writeStage(cur ^ 1);
        __syncthreads();
    }

    // ---- norms into (now free) buffer-0 regions, as f32 ----
    float* f1n = reinterpret_cast<float*>(&sf1[0][0][0][0]);   // [8][68]
    float* f2n = reinterpret_cast<float*>(&sf2[0][0][0][0]);   // [16][84]
    if (isStage) {
        float* p = isF1 ? &f1n[srow * 68 + squad * 4] : &f2n[srow * 84 + squad * 4];
        *reinterpret_cast<float4*>(p) = nsq;
    }
    __syncthreads();

    float inv1[WPT];
#pragma unroll
    for (int wi = 0; wi < WPT; ++wi) {
        const float nv = f1n[hs * 68 + wg * 8 + wi];
        inv1[wi] = 1.0f / fmaxf(sqrtf(nv), 1e-12f);
    }
    float inv2[24];
#pragma unroll
    for (int k = 0; k < 24; ++k) {
        const float nv = f2n[(hs + dyi) * 84 + wg * 8 + k];
        inv2[k] = 1.0f / fmaxf(sqrtf(nv), 1e-12f);
    }

    const int h = h0 + hs;
#pragma unroll
    for (int d = 0; d < ND; ++d) {
        float o[WPT];
#pragma unroll
        for (int wi = 0; wi < WPT; ++wi)
            o[wi] = acc[wi][d] * inv1[wi] * inv2[wi + d];
        float* op = outg + (((size_t)b * 81 + dyi * ND + d) * H_ + h) * W_ + w0 + wg * 8;
        *reinterpret_cast<float4*>(&op[0]) = make_float4(o[0], o[1], o[2], o[3]);
        *reinterpret_cast<float4*>(&op[4]) = make_float4(o[4], o[5], o[6], o[7]);
    }
}

} // namespace

extern "C" void kernel_launch(void* const* d_in, const int* in_sizes, int n_in,
                              void* d_out, int out_size, void* d_ws, size_t ws_size,
                              hipStream_t stream)
{
    (void)in_sizes; (void)n_in; (void)d_ws; (void)ws_size; (void)out_size;
    const float* f1 = (const float*)d_in[0];
    const float* f2 = (const float*)d_in[1];
    float* out = (float*)d_out;

    dim3 grid(384, 1, 1);      // flattened; XCD-chunk swizzle inside kernel
    dim3 block(NTHREADS);      // 576 threads = 9 waves (wave = dy)
    local_corr_kernel<<<grid, block, 0, stream>>>(f1, f2, out);
}

// Round 4
// 217.345 us; speedup vs baseline: 5.5500x; 2.5014x over previous
//
#include <hip/hip_runtime.h>
#include <math.h>

namespace {

constexpr int B_ = 8, C_ = 256, H_ = 128, W_ = 192;
constexpr int HW = H_ * W_;
constexpr int ND = 9;                  // 2R+1
constexpr int TH = 8;                  // h rows per block
constexpr int TW = 32;                 // w cols per block
constexpr int NTHREADS = 576;          // 9 waves, wave = dy
constexpr int KC = 4;                  // channels per chunk (2 f16-pairs)
constexpr int NCHUNK = C_ / KC;        // 64
constexpr int F1S = 36;                // u32 row stride: 9 (odd) 16B slots
constexpr int F2R = 16;                // staged f2 rows
constexpr int F2S = 52;                // u32 row stride: 13 (odd) slots
constexpr int F1SEC = TH * F1S;        // 288 u32 per parity section
constexpr int F2SEC = F2R * F2S;       // 832 u32 per parity section
constexpr int NSLOTS = 512;            // staging threads (waves 0-7)

typedef _Float16 h2 __attribute__((ext_vector_type(2)));

__device__ __forceinline__ unsigned pk2(float x, float y) {
#if __has_builtin(__builtin_amdgcn_cvt_pkrtz)
    return __builtin_bit_cast(unsigned, __builtin_amdgcn_cvt_pkrtz(x, y));
#else
    h2 t; t.x = (_Float16)x; t.y = (_Float16)y;
    return __builtin_bit_cast(unsigned, t);
#endif
}

__device__ __forceinline__ float dot2f(unsigned a, unsigned b, float c) {
#if __has_builtin(__builtin_amdgcn_fdot2)
    return __builtin_amdgcn_fdot2(__builtin_bit_cast(h2, a),
                                  __builtin_bit_cast(h2, b), c, false);
#else
    const h2 ha = __builtin_bit_cast(h2, a), hb = __builtin_bit_cast(h2, b);
    return fmaf((float)ha.x, (float)hb.x, fmaf((float)ha.y, (float)hb.y, c));
#endif
}

__global__ __launch_bounds__(NTHREADS)
void local_corr_kernel(const float* __restrict__ f1g,
                       const float* __restrict__ f2g,
                       float* __restrict__ outg)
{
    __shared__ unsigned sf1[2][2][TH][F1S];   //  4.6 KB  [buf][cpair][row][col]
    __shared__ unsigned sf2[2][2][F2R][F2S];  // 13.3 KB

    // XCD swizzle: batch image b == XCD id (96 blocks = one full image per XCD)
    const int m  = blockIdx.x;            // 0..767
    const int k  = m >> 3;                // 0..95 within XCD
    const int b  = m & 7;
    const int bx = k % 6;
    const int by = k / 6;                 // 0..15
    const int w0 = bx * TW;
    const int h0 = by * TH;

    const int tid  = threadIdx.x;
    const int dyi  = tid >> 6;            // wave = dy index 0..8
    const int lane = tid & 63;
    const int hs   = lane >> 3;           // 0..7
    const int wg   = lane & 7;            // 0..7 -> w = w0 + wg*4 + wi

    // ---- staging role: fixed (parity p, row, w-quad) across all chunks ----
    const bool isStage = tid < NSLOTS;
    const bool isF1    = tid < 128;
    int p = 0, sr = 0, wq = 0;
    if (isF1) {
        p = tid >> 6; sr = (tid >> 3) & 7; wq = tid & 7;       // 2 x 8r x 8q
    } else {
        const int s = tid - 128;                               // 0..383
        p = s >= 192 ? 1 : 0;
        const int q = s - 192 * p;                             // 0..191
        sr = q / 12; wq = q % 12;                              // 16r x 12q
    }
    const int gh = isF1 ? (h0 + sr) : (h0 - 4 + sr);
    const int gw = isF1 ? (w0 + wq * 4) : (w0 - 8 + wq * 4);
    const float* gsrc = isF1 ? f1g : f2g;
    const bool rok = (gh >= 0) && (gh < H_);
    const bool mk0 = rok && (gw + 0 >= 0) && (gw + 0 < W_);
    const bool mk1 = rok && (gw + 1 >= 0) && (gw + 1 < W_);
    const bool mk2 = rok && (gw + 2 >= 0) && (gw + 2 < W_);
    const bool mk3 = rok && (gw + 3 >= 0) && (gw + 3 < W_);
    const int ghc = gh < 0 ? 0 : (gh >= H_ ? H_ - 1 : gh);
    const int gwc = gw < 0 ? 0 : (gw > W_ - 4 ? W_ - 4 : gw);
    const size_t gBase = (size_t)b * C_ * HW + (size_t)ghc * W_ + gwc;

    float4 lo, hi;                         // in-flight loads (channel c, c+1)
    float4 nsq = make_float4(0.f, 0.f, 0.f, 0.f);

    auto issueLoads = [&](int c0) {
        const float* pa = gsrc + gBase + (size_t)(c0 + 2 * p) * HW;
        lo = *reinterpret_cast<const float4*>(pa);
        hi = *reinterpret_cast<const float4*>(pa + HW);
    };

    auto writeStage = [&](int buf) {
        const float x0 = mk0 ? lo.x : 0.f, y0 = mk0 ? hi.x : 0.f;
        const float x1 = mk1 ? lo.y : 0.f, y1 = mk1 ? hi.y : 0.f;
        const float x2 = mk2 ? lo.z : 0.f, y2 = mk2 ? hi.z : 0.f;
        const float x3 = mk3 ? lo.w : 0.f, y3 = mk3 ? hi.w : 0.f;
        const unsigned u0 = pk2(x0, y0), u1 = pk2(x1, y1);
        const unsigned u2 = pk2(x2, y2), u3 = pk2(x3, y3);
        nsq.x = dot2f(u0, u0, nsq.x);      // converted-value norms: bias cancels
        nsq.y = dot2f(u1, u1, nsq.y);
        nsq.z = dot2f(u2, u2, nsq.z);
        nsq.w = dot2f(u3, u3, nsq.w);
        unsigned* dst = isF1 ? &sf1[buf][p][sr][wq * 4] : &sf2[buf][p][sr][wq * 4];
        *reinterpret_cast<uint4*>(dst) = make_uint4(u0, u1, u2, u3);
    };

    float acc[4][ND];
#pragma unroll
    for (int i = 0; i < 4; ++i)
#pragma unroll
        for (int j = 0; j < ND; ++j) acc[i][j] = 0.f;

    const int f1off = hs * F1S + wg * 4;              // u32 index, 16B aligned
    const int f2off = (hs + dyi) * F2S + wg * 4 + 4;  // window start (dx=-4)

    auto computeChunk = [&](int buf) {
#pragma unroll
        for (int cp = 0; cp < 2; ++cp) {
            const uint4 ua = *reinterpret_cast<const uint4*>(&sf1[buf][cp][0][0] + f1off);
            const uint4* q2 = reinterpret_cast<const uint4*>(&sf2[buf][cp][0][0] + f2off);
            const uint4 v0 = q2[0], v1 = q2[1], v2 = q2[2];
            const unsigned av[4]  = {ua.x, ua.y, ua.z, ua.w};
            const unsigned vv[12] = {v0.x, v0.y, v0.z, v0.w,
                                     v1.x, v1.y, v1.z, v1.w,
                                     v2.x, v2.y, v2.z, v2.w};
#pragma unroll
            for (int wi = 0; wi < 4; ++wi)
#pragma unroll
                for (int d = 0; d < ND; ++d)
                    acc[wi][d] = dot2f(av[wi], vv[wi + d], acc[wi][d]);
        }
    };

    // ---- main loop: issue(t+1) -> compute(t) -> pack+write(t+1) -> barrier ----
    if (isStage) { issueLoads(0); writeStage(0); }
    __syncthreads();
    for (int t = 0; t < NCHUNK; ++t) {
        const bool more = (t + 1) < NCHUNK;
        if (isStage && more) issueLoads((t + 1) * KC);
        computeChunk(t & 1);
        if (isStage && more) writeStage((t + 1) & 1);
        __syncthreads();
    }

    // ---- per-position squared norms (parity-partial) into buffer 0 ----
    float* f1n = reinterpret_cast<float*>(&sf1[0][0][0][0]);  // [2][8][36]
    float* f2n = reinterpret_cast<float*>(&sf2[0][0][0][0]);  // [2][16][52]
    if (isStage) {
        float* np = isF1 ? (f1n + p * F1SEC + sr * F1S + wq * 4)
                         : (f2n + p * F2SEC + sr * F2S + wq * 4);
        *reinterpret_cast<float4*>(np) = nsq;
    }
    __syncthreads();

    float inv1[4];
#pragma unroll
    for (int wi = 0; wi < 4; ++wi) {
        const int c1 = hs * F1S + wg * 4 + wi;
        const float nv = f1n[c1] + f1n[F1SEC + c1];
        inv1[wi] = 1.0f / fmaxf(sqrtf(nv), 1e-12f);
    }
    float inv2[12];
#pragma unroll
    for (int kk = 0; kk < 12; ++kk) {
        const int c2 = (hs + dyi) * F2S + wg * 4 + 4 + kk;
        const float nv = f2n[c2] + f2n[F2SEC + c2];
        inv2[kk] = 1.0f / fmaxf(sqrtf(nv), 1e-12f);
    }

    const int h = h0 + hs;
#pragma unroll
    for (int d = 0; d < ND; ++d) {
        float o[4];
#pragma unroll
        for (int wi = 0; wi < 4; ++wi)
            o[wi] = acc[wi][d] * inv1[wi] * inv2[wi + d];
        float* op = outg + ((size_t)(b * 81 + dyi * ND + d) * H_ + h) * W_ + w0 + wg * 4;
        *reinterpret_cast<float4*>(op) = make_float4(o[0], o[1], o[2], o[3]);
    }
}

} // namespace

extern "C" void kernel_launch(void* const* d_in, const int* in_sizes, int n_in,
                              void* d_out, int out_size, void* d_ws, size_t ws_size,
                              hipStream_t stream)
{
    (void)in_sizes; (void)n_in; (void)d_ws; (void)ws_size; (void)out_size;
    const float* f1 = (const float*)d_in[0];
    const float* f2 = (const float*)d_in[1];
    float* out = (float*)d_out;

    dim3 grid(768, 1, 1);      // 6x16x8 tiles, XCD-chunked inside kernel
    dim3 block(NTHREADS);      // 576 threads = 9 waves (wave = dy)
    local_corr_kernel<<<grid, block, 0, stream>>>(f1, f2, out);
}